// Round 16
// baseline (51.903 us; speedup 1.0000x reference)
//
#include <hip/hip_runtime.h>

#define BB 8
#define HH 512
#define WW 512
#define HW (HH * WW)

typedef float f32x2 __attribute__((ext_vector_type(2)));

__device__ __forceinline__ int reflect512(int v) {
    v = v < 0 ? -v : v;
    return v >= 512 ? 1022 - v : v;
}

// unnormalized 1-D spatial gaussian samples (sigma=21)
#define S0 1.0f
#define S1 0.99886688f
#define S2 0.99547514f
#define S3 0.98984784f
// exp(-0.005*d2) ~= 1 + C1*d2 + C2*d2^2, |err| <= 1.5e-5 for d<=3 (R5-proven)
#define C1S (-5.0e-3f)
#define C2S (1.25e-5f)

__device__ __forceinline__ float swxf(int dx) {
    const float SW[7] = {S3, S2, S1, S0, S1, S2, S3};
    return (dx < -3 || dx > 3) ? 0.0f : SW[dx + 3];
}

// Interior: each PAIR of lanes (L, L^32) computes the same two pixels
// A=(y,e-1), B=(y,e). sel=0 handles window cols 0-3, sel=1 cols 4-7;
// partial sums merge via ds_bpermute(lane^32) — no LDS alloc, no barrier.
// Row weight wj folds into poly coeffs (compile-time); column weights are
// applied once in the epilogue (0-slots mask the out-of-window columns).
__global__ __launch_bounds__(256) void bilateral_split(const float* __restrict__ in,
                                                       float* __restrict__ out) {
    const int blk = blockIdx.x;
    if (blk < 8192) {
        // XCD swizzle: blk%8 = XCD -> XCD k walks image k in y-order
        const int swz  = (blk & 7) * 1024 + (blk >> 3);
        const int b    = swz >> 10;
        const int rest = swz & 1023;
        const int y    = rest >> 1;
        const int h    = rest & 1;
        const int lane = threadIdx.x & 63;
        const int sel  = lane >> 5;                       // column half
        const int pk   = ((threadIdx.x >> 6) << 5) | (lane & 31);  // pair id
        const int nact = h ? 126 : 127;
        if (pk >= nact) return;                           // both lanes exit
        const int e  = 4 + 254 * h + 2 * pk;              // B col; A = e-1
        const int cb = e - 4 + 4 * sel;                   // this half's cols

        const float* __restrict__ p0 = in + (size_t)(3 * b) * HW;
        const float* __restrict__ p1 = p0 + HW;
        const float* __restrict__ p2 = p1 + HW;

        // centers (both halves need both arms' centers)
        const int crow = y * WW;
        f32x2 m0 = *(const f32x2*)(p0 + crow + e - 2);
        f32x2 m1 = *(const f32x2*)(p1 + crow + e - 2);
        f32x2 m2 = *(const f32x2*)(p2 + crow + e - 2);
        f32x2 g0 = *(const f32x2*)(p0 + crow + e);
        f32x2 g1 = *(const f32x2*)(p1 + crow + e);
        f32x2 g2 = *(const f32x2*)(p2 + crow + e);
        const float cc[2][3] = {{m0.y, m1.y, m2.y}, {g0.x, g1.x, g2.x}};

        f32x2 aN[2][2][3], aD[2][2];          // [arm][ii][ch] — static idx only
        #pragma unroll
        for (int a = 0; a < 2; ++a)
            #pragma unroll
            for (int ii = 0; ii < 2; ++ii) {
                aN[a][ii][0] = (f32x2){0.f, 0.f};
                aN[a][ii][1] = (f32x2){0.f, 0.f};
                aN[a][ii][2] = (f32x2){0.f, 0.f};
                aD[a][ii]    = (f32x2){0.f, 0.f};
            }

        const float WJ[7] = {S3, S2, S1, S0, S1, S2, S3};

        #pragma unroll
        for (int j = 0; j < 7; ++j) {
            const int rb = reflect512(y - 3 + j) * WW + cb;
            f32x2 q[2][3];
            q[0][0] = *(const f32x2*)(p0 + rb);
            q[0][1] = *(const f32x2*)(p1 + rb);
            q[0][2] = *(const f32x2*)(p2 + rb);
            q[1][0] = *(const f32x2*)(p0 + rb + 2);
            q[1][1] = *(const f32x2*)(p1 + rb + 2);
            q[1][2] = *(const f32x2*)(p2 + rb + 2);

            // wj folded into poly coeffs: w = wj + wj*C1*d2 + wj*C2*d2^2
            const f32x2 PJ2 = {WJ[j] * C2S, WJ[j] * C2S};
            const f32x2 PJ1 = {WJ[j] * C1S, WJ[j] * C1S};
            const f32x2 PJ0 = {WJ[j], WJ[j]};

            #pragma unroll
            for (int ii = 0; ii < 2; ++ii) {
                const f32x2 v0 = q[ii][0], v1 = q[ii][1], v2 = q[ii][2];
                #pragma unroll
                for (int a = 0; a < 2; ++a) {
                    float dlo = fabsf(v0.x - cc[a][0]) + fabsf(v1.x - cc[a][1]) +
                                fabsf(v2.x - cc[a][2]);
                    float dhi = fabsf(v0.y - cc[a][0]) + fabsf(v1.y - cc[a][1]) +
                                fabsf(v2.y - cc[a][2]);
                    f32x2 dp = {dlo, dhi};
                    f32x2 d2 = dp * dp;
                    f32x2 t  = PJ2 * d2 + PJ1;     // pk_fma
                    f32x2 w  = t * d2 + PJ0;       // pk_fma
                    aN[a][ii][0] += w * v0;
                    aN[a][ii][1] += w * v1;
                    aN[a][ii][2] += w * v2;
                    aD[a][ii]    += w;
                }
            }
        }

        // column weights (incl. masking zeros), sel-dependent, applied once
        const f32x2 wcA0 = sel ? (f32x2){S1, S2} : (f32x2){S3, S2};
        const f32x2 wcA1 = sel ? (f32x2){S3, 0.f} : (f32x2){S1, S0};
        const f32x2 wcB0 = sel ? (f32x2){S0, S1} : (f32x2){0.f, S3};
        const f32x2 wcB1 = sel ? (f32x2){S2, S3} : (f32x2){S2, S1};

        f32x2 rA[4], rB[4];
        #pragma unroll
        for (int ch = 0; ch < 3; ++ch) {
            rA[ch] = wcA0 * aN[0][0][ch] + wcA1 * aN[0][1][ch];
            rB[ch] = wcB0 * aN[1][0][ch] + wcB1 * aN[1][1][ch];
        }
        rA[3] = wcA0 * aD[0][0] + wcA1 * aD[0][1];
        rB[3] = wcB0 * aD[1][0] + wcB1 * aD[1][1];

        // merge halves: partner lane = lane ^ 32 (same pair, always active)
        const int paddr = (lane ^ 32) << 2;
        #pragma unroll
        for (int v = 0; v < 4; ++v) {
            rA[v].x += __int_as_float(__builtin_amdgcn_ds_bpermute(paddr, __float_as_int(rA[v].x)));
            rA[v].y += __int_as_float(__builtin_amdgcn_ds_bpermute(paddr, __float_as_int(rA[v].y)));
            rB[v].x += __int_as_float(__builtin_amdgcn_ds_bpermute(paddr, __float_as_int(rB[v].x)));
            rB[v].y += __int_as_float(__builtin_amdgcn_ds_bpermute(paddr, __float_as_int(rB[v].y)));
        }

        if (sel == 0) {
            const float iA = 1.0f / (rA[3].x + rA[3].y);
            const float iB = 1.0f / (rB[3].x + rB[3].y);
            size_t ob = (size_t)(3 * b) * HW + crow;
            out[ob + e - 1]          = (rA[0].x + rA[0].y) * iA;
            out[ob + HW + e - 1]     = (rA[1].x + rA[1].y) * iA;
            out[ob + 2 * HW + e - 1] = (rA[2].x + rA[2].y) * iA;
            out[ob + e]              = (rB[0].x + rB[0].y) * iB;
            out[ob + HW + e]         = (rB[1].x + rB[1].y) * iB;
            out[ob + 2 * HW + e]     = (rB[2].x + rB[2].y) * iB;
        }
    } else {
        // ---- border path: columns {0,1,2,509,510,511}, all rows/batches ----
        int idx  = (blk - 8192) * 256 + threadIdx.x;   // exactly 24576
        int ci   = idx % 6;
        int rest = idx / 6;
        int y = rest & 511;
        int b = rest >> 9;
        int x = ci < 3 ? ci : 506 + ci;

        const float* __restrict__ p0 = in + (size_t)(3 * b) * HW;
        const float* __restrict__ p1 = p0 + HW;
        const float* __restrict__ p2 = p1 + HW;
        int cidx = y * WW + x;
        float c0 = p0[cidx], c1 = p1[cidx], c2 = p2[cidx];
        float n0 = 0.f, n1 = 0.f, n2 = 0.f, dn = 0.f;
        #pragma unroll
        for (int dy = 0; dy < 7; ++dy) {
            int rbase = reflect512(y + dy - 3) * WW;
            float wy = swxf(dy - 3);
            #pragma unroll
            for (int dx = 0; dx < 7; ++dx) {
                int o = rbase + reflect512(x + dx - 3);
                float q0 = p0[o], q1 = p1[o], q2 = p2[o];
                float d  = fabsf(q0 - c0) + fabsf(q1 - c1) + fabsf(q2 - c2);
                float d2 = d * d;
                float w  = wy * swxf(dx - 3) * fmaf(fmaf(C2S, d2, C1S), d2, 1.0f);
                n0 += w * q0; n1 += w * q1; n2 += w * q2; dn += w;
            }
        }
        float inv = 1.0f / dn;
        size_t ob = (size_t)(3 * b) * HW + cidx;
        out[ob] = n0 * inv; out[ob + HW] = n1 * inv; out[ob + 2 * HW] = n2 * inv;
    }
}

extern "C" void kernel_launch(void* const* d_in, const int* in_sizes, int n_in,
                              void* d_out, int out_size, void* d_ws, size_t ws_size,
                              hipStream_t stream) {
    const float* in = (const float*)d_in[0];
    float* out = (float*)d_out;
    // 8192 interior blocks (8 img x 512 rows x 2 col-halves) + 96 border
    int blocks = 8192 + 96;
    bilateral_split<<<blocks, 256, 0, stream>>>(in, out);
}

// Round 17
// 42.778 us; speedup vs baseline: 1.2133x; 1.2133x over previous
//
#include <hip/hip_runtime.h>

#define BB 8
#define HH 512
#define WW 512
#define HW (HH * WW)

typedef float f32x2 __attribute__((ext_vector_type(2)));
typedef float f32x4 __attribute__((ext_vector_type(4)));

__device__ __forceinline__ int reflect512(int v) {
    v = v < 0 ? -v : v;
    return v >= 512 ? 1022 - v : v;
}

// unnormalized 1-D spatial gaussian (sigma=21); out-of-window -> 0 (mask)
__device__ __forceinline__ float swx(int dx) {
    const float SW[7] = {0.98984784f, 0.99547514f, 0.99886688f, 1.0f,
                         0.99886688f, 0.99547514f, 0.98984784f};
    return (dx < -3 || dx > 3) ? 0.0f : SW[dx + 3];
}

// exp(-0.005*d2) ~= 1 + C1*d2 + C2*d2^2, |err| <= 1.5e-5 for d<=3 (R5-proven)
#define C1S (-5.0e-3f)
#define C2S (1.25e-5f)

// 2 rows x 4 cols = 8 px/thread. Window rows loaded once as 3x dwordx4 per
// channel feed both output rows and all 4 centers. Spatial weights folded
// fully into per-tap poly coeffs (compile-time); inactive (pair,center)
// combos pruned at compile time. Stores coalesced dwordx4.
__global__ __launch_bounds__(256) void bilateral_q8(const float* __restrict__ in,
                                                    float* __restrict__ out) {
    const int blk = blockIdx.x;
    if (blk < 1024) {
        // XCD swizzle: blk%8 = XCD -> XCD k walks image k in y-order (R13/R14)
        const int b   = blk & 7;
        const int rp2 = blk >> 3;                 // 0..127
        const int sub = threadIdx.x >> 7;         // 0..1
        const int c   = threadIdx.x & 127;        // col group
        if (c == 0 || c == 127) return;           // cols 0-3,508-511 -> border path
        const int y0 = rp2 * 4 + sub * 2;         // rows y0, y0+1
        const int x0 = 4 * c;                     // cols x0..x0+3 (4..504)
        const int xl = x0 - 4;                    // leftmost loaded col, 16B aligned

        const float* __restrict__ p0 = in + (size_t)(3 * b) * HW;
        const float* __restrict__ p1 = p0 + HW;
        const float* __restrict__ p2 = p1 + HW;

        // centers cc[row][ch][k] for 4 pixels per row
        float cc[2][3][4];
        #pragma unroll
        for (int row = 0; row < 2; ++row) {
            const int cb = (y0 + row) * WW + x0;
            f32x4 C0 = *(const f32x4*)(p0 + cb);
            f32x4 C1 = *(const f32x4*)(p1 + cb);
            f32x4 C2 = *(const f32x4*)(p2 + cb);
            cc[row][0][0]=C0.x; cc[row][0][1]=C0.y; cc[row][0][2]=C0.z; cc[row][0][3]=C0.w;
            cc[row][1][0]=C1.x; cc[row][1][1]=C1.y; cc[row][1][2]=C1.z; cc[row][1][3]=C1.w;
            cc[row][2][0]=C2.x; cc[row][2][1]=C2.y; cc[row][2][2]=C2.z; cc[row][2][3]=C2.w;
        }

        // acc[row][k][v], v = ch0,ch1,ch2,den — packed column pairs
        f32x2 acc[2][4][4];
        #pragma unroll
        for (int row = 0; row < 2; ++row)
            #pragma unroll
            for (int k = 0; k < 4; ++k)
                #pragma unroll
                for (int v = 0; v < 4; ++v) acc[row][k][v] = (f32x2){0.f, 0.f};

        const float SWT[7] = {0.98984784f, 0.99547514f, 0.99886688f, 1.0f,
                              0.99886688f, 0.99547514f, 0.98984784f};

        #pragma unroll
        for (int r = 0; r < 8; ++r) {             // staged rows y0-3 .. y0+4
            const int rb = reflect512(y0 - 3 + r) * WW + xl;
            f32x4 L0a = *(const f32x4*)(p0 + rb);
            f32x4 L0b = *(const f32x4*)(p0 + rb + 4);
            f32x4 L0c = *(const f32x4*)(p0 + rb + 8);
            f32x4 L1a = *(const f32x4*)(p1 + rb);
            f32x4 L1b = *(const f32x4*)(p1 + rb + 4);
            f32x4 L1c = *(const f32x4*)(p1 + rb + 8);
            f32x4 L2a = *(const f32x4*)(p2 + rb);
            f32x4 L2b = *(const f32x4*)(p2 + rb + 4);
            f32x4 L2c = *(const f32x4*)(p2 + rb + 8);
            // column pairs q[P][ch], P=0..5 over cols xl+2P, xl+2P+1
            f32x2 q[6][3];
            q[0][0]=(f32x2){L0a.x,L0a.y}; q[1][0]=(f32x2){L0a.z,L0a.w};
            q[2][0]=(f32x2){L0b.x,L0b.y}; q[3][0]=(f32x2){L0b.z,L0b.w};
            q[4][0]=(f32x2){L0c.x,L0c.y}; q[5][0]=(f32x2){L0c.z,L0c.w};
            q[0][1]=(f32x2){L1a.x,L1a.y}; q[1][1]=(f32x2){L1a.z,L1a.w};
            q[2][1]=(f32x2){L1b.x,L1b.y}; q[3][1]=(f32x2){L1b.z,L1b.w};
            q[4][1]=(f32x2){L1c.x,L1c.y}; q[5][1]=(f32x2){L1c.z,L1c.w};
            q[0][2]=(f32x2){L2a.x,L2a.y}; q[1][2]=(f32x2){L2a.z,L2a.w};
            q[2][2]=(f32x2){L2b.x,L2b.y}; q[3][2]=(f32x2){L2b.z,L2b.w};
            q[4][2]=(f32x2){L2c.x,L2c.y}; q[5][2]=(f32x2){L2c.z,L2c.w};

            #pragma unroll
            for (int row = 0; row < 2; ++row) {
                const int dy = r - row;           // window row index 0..6
                if (dy < 0 || dy > 6) continue;   // statically eliminated
                const float wj = SWT[dy];
                #pragma unroll
                for (int k = 0; k < 4; ++k) {
                    #pragma unroll
                    for (int P = 0; P < 6; ++P) {
                        const float wlo = swx(2 * P - 4 - k);
                        const float whi = swx(2 * P - 3 - k);
                        if (wlo == 0.f && whi == 0.f) continue;  // pruned
                        // fully folded coeffs (compile-time constants)
                        const f32x2 A2c = {wj * wlo * C2S, wj * whi * C2S};
                        const f32x2 A1c = {wj * wlo * C1S, wj * whi * C1S};
                        const f32x2 A0c = {wj * wlo,       wj * whi};
                        const float k0 = cc[row][0][k], k1 = cc[row][1][k], k2 = cc[row][2][k];
                        float dlo = fabsf(q[P][0].x - k0) + fabsf(q[P][1].x - k1) +
                                    fabsf(q[P][2].x - k2);
                        float dhi = fabsf(q[P][0].y - k0) + fabsf(q[P][1].y - k1) +
                                    fabsf(q[P][2].y - k2);
                        f32x2 dp = {dlo, dhi};
                        f32x2 z  = dp * dp;                  // pk_mul
                        f32x2 w  = (A2c * z + A1c) * z + A0c; // 2x pk_fma
                        acc[row][k][0] += w * q[P][0];
                        acc[row][k][1] += w * q[P][1];
                        acc[row][k][2] += w * q[P][2];
                        acc[row][k][3] += w;
                    }
                }
            }
        }

        #pragma unroll
        for (int row = 0; row < 2; ++row) {
            f32x4 o0, o1, o2;
            #pragma unroll
            for (int k = 0; k < 4; ++k) {
                const float inv = 1.0f / (acc[row][k][3].x + acc[row][k][3].y);
                const float v0 = (acc[row][k][0].x + acc[row][k][0].y) * inv;
                const float v1 = (acc[row][k][1].x + acc[row][k][1].y) * inv;
                const float v2 = (acc[row][k][2].x + acc[row][k][2].y) * inv;
                if (k == 0) { o0.x = v0; o1.x = v1; o2.x = v2; }
                if (k == 1) { o0.y = v0; o1.y = v1; o2.y = v2; }
                if (k == 2) { o0.z = v0; o1.z = v1; o2.z = v2; }
                if (k == 3) { o0.w = v0; o1.w = v1; o2.w = v2; }
            }
            size_t ob = (size_t)(3 * b) * HW + (size_t)(y0 + row) * WW + x0;
            *(f32x4*)(out + ob)          = o0;
            *(f32x4*)(out + ob + HW)     = o1;
            *(f32x4*)(out + ob + 2*HW)   = o2;
        }
    } else {
        // ---- border path: columns {0,1,2,3,508,509,510,511} ----
        int idx  = (blk - 1024) * 256 + threadIdx.x;   // exactly 32768
        int ci   = idx & 7;
        int rest = idx >> 3;
        int y = rest & 511;
        int b = rest >> 9;
        int x = ci < 4 ? ci : 504 + ci;

        const float* __restrict__ p0 = in + (size_t)(3 * b) * HW;
        const float* __restrict__ p1 = p0 + HW;
        const float* __restrict__ p2 = p1 + HW;
        int cidx = y * WW + x;
        float c0 = p0[cidx], c1 = p1[cidx], c2 = p2[cidx];
        float n0 = 0.f, n1 = 0.f, n2 = 0.f, dn = 0.f;
        #pragma unroll
        for (int dy = 0; dy < 7; ++dy) {
            int rbase = reflect512(y + dy - 3) * WW;
            float wy = swx(dy - 3);
            #pragma unroll
            for (int dx = 0; dx < 7; ++dx) {
                int o = rbase + reflect512(x + dx - 3);
                float q0 = p0[o], q1 = p1[o], q2 = p2[o];
                float d  = fabsf(q0 - c0) + fabsf(q1 - c1) + fabsf(q2 - c2);
                float d2 = d * d;
                float w  = wy * swx(dx - 3) * fmaf(fmaf(C2S, d2, C1S), d2, 1.0f);
                n0 += w * q0; n1 += w * q1; n2 += w * q2; dn += w;
            }
        }
        float inv = 1.0f / dn;
        size_t ob = (size_t)(3 * b) * HW + cidx;
        out[ob] = n0 * inv; out[ob + HW] = n1 * inv; out[ob + 2 * HW] = n2 * inv;
    }
}

extern "C" void kernel_launch(void* const* d_in, const int* in_sizes, int n_in,
                              void* d_out, int out_size, void* d_ws, size_t ws_size,
                              hipStream_t stream) {
    const float* in = (const float*)d_in[0];
    float* out = (float*)d_out;
    // 1024 interior blocks (8 img x 128 row-quads) + 128 border blocks
    int blocks = 1024 + 128;
    bilateral_q8<<<blocks, 256, 0, stream>>>(in, out);
}